// Round 10
// baseline (457.031 us; speedup 1.0000x reference)
//
#include <hip/hip_runtime.h>

// spectralAgg R10: INSTRUMENTED ROUND.
// Main kernel = R4 monolithic (proven 378us, absmax 0.03125), unchanged.
// Prepended: four pure-read probe kernels (each writes throwaway sums into
// d_out, which the main kernel fully overwrites afterwards) to isolate the
// HBM read-rate of each access pattern in the rocprof per-dispatch rows:
//   p_seq pass1 : 128MB sequential cold          (expect ~6.3 TB/s)
//   p_seq pass2 : 256MB over same region, L3-hot (measures L3 read BW)
//   p_patch     : exact R4 phase-1 patch loader  (hypothesis: ~2.6 TB/s)
//   p_row       : 2KB-contiguous-per-c, c-major  (intermediate?)
// No d_ws use -> no giant fill dispatches hiding the counter rows.

#define NW  512
#define HWs 262144
#define NS1 16
#define NS3 16

typedef __attribute__((ext_vector_type(4)))  __bf16 bf4;
typedef __attribute__((ext_vector_type(8)))  __bf16 bf8;
typedef __attribute__((ext_vector_type(16))) float  f32x16;

#define MFMA __builtin_amdgcn_mfma_f32_32x32x16_bf16
#define F4E(v,j) ((j)==0?(v).x:(j)==1?(v).y:(j)==2?(v).z:(v).w)

__device__ __forceinline__ void bar_lgkm() {
  asm volatile("s_waitcnt lgkmcnt(0)" ::: "memory");
  __builtin_amdgcn_s_barrier();
}

// ========================= probes =========================
extern "C" __global__ __launch_bounds__(256)
void p_seq(const float4* __restrict__ x, float* __restrict__ dout, int nPass) {
  const int gid = blockIdx.x * 256 + threadIdx.x;
  const int stride = gridDim.x * 256;
  float acc = 0.f;
  for (int ps = 0; ps < nPass; ++ps)
    for (int i = gid; i < 8388608; i += stride) {   // 128MB of x
      const float4 v = x[i];
      acc += v.x + v.y + v.z + v.w;
    }
  dout[gid] = acc;
}

extern "C" __global__ __launch_bounds__(256)
void p_patch(const float* __restrict__ x, float* __restrict__ dout) {
  const int wg = blockIdx.x;               // 128 WGs -> 128 spread patches, 128MB
  const int pid = wg * 4 + (wg & 3);       // covers all 8 pc classes
  const int b = pid >> 6, pp = pid & 63, pr = pp >> 3, pc = pp & 7;
  const float* xp = x + (size_t)b * 64 * HWs + (size_t)(pr * 64) * NW + pc * 64;
  const int t = threadIdx.x;
  const int c_ld = t >> 2, q_ld = t & 3;
  const float* g1 = xp + (size_t)c_ld * HWs + q_ld * 16;
  float acc = 0.f;
  for (int st = 0; st < 16; ++st) {
#pragma unroll
    for (int rl = 0; rl < 4; ++rl)
#pragma unroll
      for (int j = 0; j < 4; ++j) {
        const float4 v = *(const float4*)(g1 + (size_t)(st * 4 + rl) * NW + j * 4);
        acc += v.x + v.y + v.z + v.w;
      }
  }
  dout[wg * 256 + t] = acc;
}

extern "C" __global__ __launch_bounds__(256)
void p_row(const float* __restrict__ x, float* __restrict__ dout) {
  const int wg = blockIdx.x;               // 128 WGs x 1MB = 128MB (imgs 0-1)
  const int img = wg >> 6, band = wg & 63;
  const int t = threadIdx.x;
  const int half = t >> 7, col = t & 127;
  const float* xb = x + (size_t)img * 64 * HWs + (size_t)(band * 8) * NW + col * 4;
  float acc = 0.f;
  for (int rp = 0; rp < 4; ++rp) {
#pragma unroll 8
    for (int c = 0; c < 64; ++c) {         // c-major burst, 2KB runs per c
      const float4 v = *(const float4*)(xb + (size_t)c * HWs + (size_t)(rp * 2 + half) * NW);
      acc += v.x + v.y + v.z + v.w;
    }
  }
  dout[wg * 256 + t] = acc;
}

// ========================= main: R4 monolithic (proven) =========================
__device__ __forceinline__ void fb_load1(const float* g1, int st, float4 (&R)[16]) {
  const float* gp = g1 + (size_t)st * 4 * NW;
#pragma unroll
  for (int rl = 0; rl < 4; ++rl)
#pragma unroll
    for (int j = 0; j < 4; ++j)
      R[rl * 4 + j] = *(const float4*)(gp + (size_t)rl * NW + j * 4);
}
__device__ __forceinline__ void fb_cvtw1(char* wH, char* wL, int q_ld, int swzw,
                                         const float4 (&R)[16]) {
#pragma unroll
  for (int rl = 0; rl < 4; ++rl)
#pragma unroll
    for (int s = 0; s < 2; ++s) {
      const float4 va = R[rl * 4 + s * 2], vb = R[rl * 4 + s * 2 + 1];
      const float f[8] = {va.x, va.y, va.z, va.w, vb.x, vb.y, vb.z, vb.w};
      bf8 h, lo;
#pragma unroll
      for (int e = 0; e < 8; ++e) { h[e] = (__bf16)f[e]; lo[e] = (__bf16)(f[e] - (float)h[e]); }
      const int boff = (rl * 128 + q_ld * 32 + s * 16) ^ swzw;
      *(bf8*)(wH + boff) = h;
      *(bf8*)(wL + boff) = lo;
    }
}
__device__ __forceinline__ void fb_load3(const float* g3, int st, float4 (&R)[16]) {
  const float* gp = g3 + (size_t)st * 4 * NW;
#pragma unroll
  for (int cc = 0; cc < 4; ++cc)
#pragma unroll
    for (int j = 0; j < 4; ++j)
      R[cc * 4 + j] = *(const float4*)(gp + (size_t)cc * HWs + j * 4);
}
__device__ __forceinline__ void fb_cvtw3(char* sT, int cg, int iq, const float4 (&R)[16]) {
#pragma unroll
  for (int w = 0; w < 16; ++w) {
    bf4 q;
#pragma unroll
    for (int cc = 0; cc < 4; ++cc) q[cc] = (__bf16)F4E(R[cc * 4 + (w >> 2)], w & 3);
    const int iloc = iq * 16 + w;
    const int sw = ((iloc & 15) ^ ((iloc >> 4) & 7)) << 4;
    const int boff = (iloc & 127) * 256 + ((((iloc >> 7) << 7) + cg * 8) ^ sw);
    *(bf4*)(sT + boff) = q;
  }
}
extern "C" __global__ __launch_bounds__(256, 2)
void spectralAgg_main(const float* __restrict__ x, const float* __restrict__ g,
                      float* __restrict__ out) {
  __shared__ char lds[73728];
  char* sH = lds;
  char* sL = lds + 32768;
  char* sA = lds + 65536;
  const int t = threadIdx.x, wv = t >> 6, l = t & 63, l31 = l & 31, hh = l >> 5;
  const int wg = blockIdx.x, b = wg >> 6, pp = wg & 63, pr = pp >> 3, pcq = pp & 7;
  const size_t pbase = (size_t)b*64*HWs + (size_t)(pr*64)*NW + (size_t)(pcq*64);
  const float* xp = x + pbase;
  float* op = out + pbase;
  const int c_ld = t >> 2, q_ld = t & 3;
  const float* g1 = xp + (size_t)c_ld * HWs + q_ld * 16;
  char* wH = sH + c_ld * 512;
  char* wL = sL + c_ld * 512;
  const int swzw = (c_ld & 31) << 4;
  const int ct = wv >> 1, dt = wv & 1;
  const char* pA  = sH + (size_t)(ct*32+l31)*512;
  const char* pBh = sH + (size_t)(dt*32+l31)*512;
  const char* pBl = sL + (size_t)(dt*32+l31)*512;
  const int swzr = l31 << 4;
  f32x16 accG, accS;
#pragma unroll
  for (int i = 0; i < 16; ++i) { accG[i] = 0.f; accS[i] = 0.f; }
  float4 ra[16], rb[16];
  fb_load1(g1, 0, ra);
  for (int st = 0; st < NS1; ++st) {
    fb_load1(g1, (st + 1 < NS1) ? st + 1 : st, rb);
    fb_cvtw1(wH, wL, q_ld, swzw, ra);
    bar_lgkm();
#pragma unroll
    for (int k0 = 0; k0 < 16; ++k0) {
      const int off = (k0 * 32 + hh * 16) ^ swzr;
      const bf8 a  = *(const bf8*)(pA + off);
      const bf8 bh = *(const bf8*)(pBh + off);
      const bf8 bl = *(const bf8*)(pBl + off);
      accG = MFMA(a, bh, accG, 0, 0, 0);
      accS = MFMA(a, bl, accS, 0, 0, 0);
    }
    bar_lgkm();
#pragma unroll
    for (int e = 0; e < 16; ++e) ra[e] = rb[e];
  }
  float* S_lds = (float*)sL;
  float* E_lds = (float*)sH;
#pragma unroll
  for (int i = 0; i < 16; ++i) {
    const int cr = ct*32 + (i&3) + ((i>>2)<<3) + (hh<<2);
    S_lds[cr*64 + dt*32 + l31] = accS[i];
  }
  bar_lgkm();
#pragma unroll
  for (int i = 0; i < 16; ++i) {
    const int cr = ct*32 + (i&3) + ((i>>2)<<3) + (hh<<2);
    const int d = dt*32 + l31;
    E_lds[cr*64 + d] = accG[i] + accS[i] + S_lds[d*64 + cr];
  }
  bar_lgkm();
  const int cg = t >> 4, iq = t & 15;
  const float* g3 = xp + (size_t)(cg*4)*HWs + (size_t)(iq>>2)*NW + (iq&3)*16;
  fb_load3(g3, 0, ra);
  const float gs = 1.0f + g[0];
#pragma unroll 1
  for (int rr = 0; rr < 16; ++rr) {
    const int c = wv*16 + rr;
    const float e = E_lds[c*64 + l];
    float mn = e;
#pragma unroll
    for (int o = 32; o; o >>= 1) mn = fminf(mn, __shfl_xor(mn, o));
    const float w = __expf(mn - e);
    float s = w;
#pragma unroll
    for (int o = 32; o; o >>= 1) s += __shfl_xor(s, o);
    *(__bf16*)(sA + c*128 + ((l*2) ^ ((c&7)<<4))) = (__bf16)(gs * w / s);
  }
  bar_lgkm();
  bf8 bfr[2][4];
#pragma unroll
  for (int c2 = 0; c2 < 2; ++c2)
#pragma unroll
    for (int k0 = 0; k0 < 4; ++k0)
      bfr[c2][k0] = *(const bf8*)(sA + (size_t)(c2*32+l31)*128 +
                                  ((k0*32 + hh*16) ^ ((l31&7)<<4)));
  for (int st = 0; st < NS3; ++st) {
    fb_load3(g3, (st + 1 < NS3) ? st + 1 : st, rb);
    fb_cvtw3(sH, cg, iq, ra);
    bar_lgkm();
    f32x16 oo0[2], oo1[2];
#pragma unroll
    for (int it = 0; it < 2; ++it)
#pragma unroll
      for (int i = 0; i < 16; ++i) { oo0[it][i] = 0.f; oo1[it][i] = 0.f; }
#pragma unroll
    for (int it = 0; it < 2; ++it) {
      const int i = wv*64 + it*32 + l31;
      const char* base = sH + (size_t)(i & 127) * 256;
      const int hb = (i >> 7) * 128;
      const int sw = ((i & 15) ^ ((i >> 4) & 7)) << 4;
#pragma unroll
      for (int k0 = 0; k0 < 4; ++k0) {
        const bf8 pa = *(const bf8*)(base + ((hb + k0*32 + hh*16) ^ sw));
        oo0[it] = MFMA(pa, bfr[0][k0], oo0[it], 0, 0, 0);
        oo1[it] = MFMA(pa, bfr[1][k0], oo1[it], 0, 0, 0);
      }
    }
#pragma unroll
    for (int it = 0; it < 2; ++it)
#pragma unroll
      for (int rq = 0; rq < 4; ++rq) {
        const int iloc = wv*64 + it*32 + rq*8 + hh*4;
        const int gi = st*256 + iloc;
        float* oprow = op + (size_t)(gi >> 6)*NW + (gi & 63);
        float4 q0; q0.x=oo0[it][rq*4+0]; q0.y=oo0[it][rq*4+1]; q0.z=oo0[it][rq*4+2]; q0.w=oo0[it][rq*4+3];
        *(float4*)(oprow + (size_t)l31*HWs) = q0;
        float4 q1; q1.x=oo1[it][rq*4+0]; q1.y=oo1[it][rq*4+1]; q1.z=oo1[it][rq*4+2]; q1.w=oo1[it][rq*4+3];
        *(float4*)(oprow + (size_t)(32+l31)*HWs) = q1;
      }
    bar_lgkm();
#pragma unroll
    for (int e = 0; e < 16; ++e) ra[e] = rb[e];
  }
}

extern "C" void kernel_launch(void* const* d_in, const int* in_sizes, int n_in,
                              void* d_out, int out_size, void* d_ws, size_t ws_size,
                              hipStream_t stream) {
  const float* x = (const float*)d_in[0];
  const float* g = (const float*)d_in[1];
  float* o = (float*)d_out;
  // probes (results thrown away; d_out fully overwritten by main afterwards)
  p_seq  <<<dim3(2048), dim3(256), 0, stream>>>((const float4*)x, o, 1);
  p_seq  <<<dim3(2048), dim3(256), 0, stream>>>((const float4*)x, o, 2);
  p_patch<<<dim3(128),  dim3(256), 0, stream>>>(x, o);
  p_row  <<<dim3(128),  dim3(256), 0, stream>>>(x, o);
  // real kernel (R4, proven)
  spectralAgg_main<<<dim3(512), dim3(256), 0, stream>>>(x, g, o);
}